// Round 16
// baseline (277.669 us; speedup 1.0000x reference)
//
#include <hip/hip_runtime.h>

#define BB 16
#define NT 2048
#define NC 2048
#define DIM 256
#define INDIM 128

typedef unsigned short u16;
typedef __bf16 bfx8 __attribute__((ext_vector_type(8)));
typedef __bf16 bfx8a __attribute__((ext_vector_type(8), aligned(8)));
typedef float f32x4 __attribute__((ext_vector_type(4)));

__device__ __forceinline__ u16 f2bf(float f) {
    union { float f; unsigned u; } v; v.f = f;
    return (u16)((v.u + 0x7FFFu + ((v.u >> 16) & 1u)) >> 16);
}

#define MFMA16(a, b, c) __builtin_amdgcn_mfma_f32_16x16x32_bf16((a), (b), (c), 0, 0, 0)

// ---------------- converts ----------------

// all six weight transposes in ONE launch: w[K][256] fp32 -> wt [256][K] bf16
__global__ void cvt_w_all(const float* __restrict__ w0, const float* __restrict__ w1,
                          const float* __restrict__ w2, const float* __restrict__ w3,
                          const float* __restrict__ w4, const float* __restrict__ w5,
                          u16* __restrict__ o0, u16* __restrict__ o1, u16* __restrict__ o2,
                          u16* __restrict__ o3, u16* __restrict__ o4, u16* __restrict__ o5) {
    int bx = blockIdx.x;
    const float* src; u16* dst; int K, base;
    if (bx < 128)       { src = w0; dst = o0; K = 128; base = 0; }
    else if (bx < 384)  { src = w1; dst = o1; K = 256; base = 128; }
    else if (bx < 640)  { src = w2; dst = o2; K = 256; base = 384; }
    else if (bx < 768)  { src = w3; dst = o3; K = 128; base = 640; }
    else if (bx < 1024) { src = w4; dst = o4; K = 256; base = 768; }
    else                { src = w5; dst = o5; K = 256; base = 1024; }
    int idx = (bx - base) * 256 + threadIdx.x;
    int n = idx / K, k = idx - n * K;
    dst[idx] = f2bf(src[k * 256 + n]);
}

// ---------------- fused 3-layer MLP, 64-row tiles (R11/R14-proven, standalone) --------

__global__ __launch_bounds__(256) void mlp_fused(const float* __restrict__ xq, const float* __restrict__ xk,
                                                 const u16* __restrict__ W1q, const u16* __restrict__ W1k,
                                                 const float* __restrict__ b1q, const float* __restrict__ b1k,
                                                 const u16* __restrict__ W2q, const u16* __restrict__ W2k,
                                                 const float* __restrict__ b2q, const float* __restrict__ b2k,
                                                 const u16* __restrict__ W3q, const u16* __restrict__ W3k,
                                                 const float* __restrict__ b3q, const float* __restrict__ b3k,
                                                 u16* __restrict__ oq, u16* __restrict__ ok) {
    __shared__ __align__(16) char lds[65536];
    char* h1 = lds;            // [64][256] bf16, 512 B rows, swizzled; later: epilogue tile
    char* xa = lds + 32768;    // [64][128] bf16, 256 B rows, swizzled
    char* h2 = lds + 32768;    // [64][256] bf16, swizzled (overlays xa after it's dead)

    int tid = threadIdx.x, lane = tid & 63, w = tid >> 6;
    int lr = lane & 15, lg = lane >> 4;
    int m0 = blockIdx.x * 64;
    bool isq = (blockIdx.y == 0);
    const float* X = (isq ? xq : xk) + (size_t)m0 * INDIM;
    const u16* W1 = isq ? W1q : W1k;  const float* b1 = isq ? b1q : b1k;
    const u16* W2 = isq ? W2q : W2k;  const float* b2 = isq ? b2q : b2k;
    const u16* W3 = isq ? W3q : W3k;  const float* b3 = isq ? b3q : b3k;
    u16* C = (isq ? oq : ok) + (size_t)m0 * 256;

    // stage x: 64x128 fp32 -> bf16 swizzled (4 chunks of 16 B per thread)
#pragma unroll
    for (int j = 0; j < 4; j++) {
        int bo = (j * 256 + tid) * 16;
        int row = bo >> 8;                        // 256 B rows
        int ir = bo & 255;
        const float* src = X + (size_t)row * INDIM + (ir >> 1);
        float4 f0 = *reinterpret_cast<const float4*>(src);
        float4 f1 = *reinterpret_cast<const float4*>(src + 4);
        union { u16 u[8]; uint4 v; } pk;
        pk.u[0] = f2bf(f0.x); pk.u[1] = f2bf(f0.y); pk.u[2] = f2bf(f0.z); pk.u[3] = f2bf(f0.w);
        pk.u[4] = f2bf(f1.x); pk.u[5] = f2bf(f1.y); pk.u[6] = f2bf(f1.z); pk.u[7] = f2bf(f1.w);
        *reinterpret_cast<uint4*>(xa + row * 256 + (ir ^ ((row & 7) << 4))) = pk.v;
    }
    __syncthreads();

    int n0 = w * 64;
    const int key = (lr & 7) << 4;

    // ---- GEMM1: h1 = relu(x @ W1^T + b1), K=128 ----
    {
        f32x4 acc[4][4] = {};
#pragma unroll
        for (int ks = 0; ks < 4; ks++) {
            bfx8 b[4];
#pragma unroll
            for (int nt = 0; nt < 4; nt++)
                b[nt] = *reinterpret_cast<const bfx8*>(W1 + (size_t)(n0 + nt * 16 + lr) * 128 + ks * 32 + lg * 8);
#pragma unroll
            for (int mt = 0; mt < 4; mt++) {
                bfx8 a = *reinterpret_cast<const bfx8*>(xa + (mt * 16 + lr) * 256 + ((ks * 64 + lg * 16) ^ key));
#pragma unroll
                for (int nt = 0; nt < 4; nt++)
                    acc[mt][nt] = MFMA16(a, b[nt], acc[mt][nt]);
            }
        }
#pragma unroll
        for (int nt = 0; nt < 4; nt++) {
            int col = n0 + nt * 16 + lr;
            float bv = b1[col];
#pragma unroll
            for (int mt = 0; mt < 4; mt++) {
#pragma unroll
                for (int r2 = 0; r2 < 4; r2++) {
                    int row = mt * 16 + lg * 4 + r2;
                    float v = fmaxf(acc[mt][nt][r2] + bv, 0.0f);
                    *(u16*)(h1 + row * 512 + ((col * 2) ^ ((row & 7) << 4))) = f2bf(v);
                }
            }
        }
    }
    __syncthreads();

    // ---- GEMM2: h2 = relu(h1 @ W2^T + b2), K=256 ----
    {
        f32x4 acc[4][4] = {};
#pragma unroll
        for (int ks = 0; ks < 8; ks++) {
            bfx8 b[4];
#pragma unroll
            for (int nt = 0; nt < 4; nt++)
                b[nt] = *reinterpret_cast<const bfx8*>(W2 + (size_t)(n0 + nt * 16 + lr) * 256 + ks * 32 + lg * 8);
#pragma unroll
            for (int mt = 0; mt < 4; mt++) {
                bfx8 a = *reinterpret_cast<const bfx8*>(h1 + (mt * 16 + lr) * 512 + ((ks * 64 + lg * 16) ^ key));
#pragma unroll
                for (int nt = 0; nt < 4; nt++)
                    acc[mt][nt] = MFMA16(a, b[nt], acc[mt][nt]);
            }
        }
#pragma unroll
        for (int nt = 0; nt < 4; nt++) {
            int col = n0 + nt * 16 + lr;
            float bv = b2[col];
#pragma unroll
            for (int mt = 0; mt < 4; mt++) {
#pragma unroll
                for (int r2 = 0; r2 < 4; r2++) {
                    int row = mt * 16 + lg * 4 + r2;
                    float v = fmaxf(acc[mt][nt][r2] + bv, 0.0f);
                    *(u16*)(h2 + row * 512 + ((col * 2) ^ ((row & 7) << 4))) = f2bf(v);
                }
            }
        }
    }
    __syncthreads();

    // ---- GEMM3: out = h2 @ W3^T + b3, K=256; epilogue via LDS (h1 dead) ----
    {
        f32x4 acc[4][4] = {};
#pragma unroll
        for (int ks = 0; ks < 8; ks++) {
            bfx8 b[4];
#pragma unroll
            for (int nt = 0; nt < 4; nt++)
                b[nt] = *reinterpret_cast<const bfx8*>(W3 + (size_t)(n0 + nt * 16 + lr) * 256 + ks * 32 + lg * 8);
#pragma unroll
            for (int mt = 0; mt < 4; mt++) {
                bfx8 a = *reinterpret_cast<const bfx8*>(h2 + (mt * 16 + lr) * 512 + ((ks * 64 + lg * 16) ^ key));
#pragma unroll
                for (int nt = 0; nt < 4; nt++)
                    acc[mt][nt] = MFMA16(a, b[nt], acc[mt][nt]);
            }
        }
        u16* ot = (u16*)h1;   // [64][256] staging for coalesced store
#pragma unroll
        for (int nt = 0; nt < 4; nt++) {
            int col = n0 + nt * 16 + lr;
            float bv = b3[col];
#pragma unroll
            for (int mt = 0; mt < 4; mt++) {
#pragma unroll
                for (int r2 = 0; r2 < 4; r2++) {
                    int row = mt * 16 + lg * 4 + r2;
                    ot[row * 256 + col] = f2bf(acc[mt][nt][r2] + bv);
                }
            }
        }
        __syncthreads();
#pragma unroll
        for (int p = 0; p < 8; p++) {
            int idx = p * 256 + tid;           // 2048 chunks of 16 B
            int row = idx >> 5, ck = idx & 31;
            *reinterpret_cast<uint4*>(C + (size_t)row * 256 + ck * 8) =
                *reinterpret_cast<const uint4*>(ot + row * 256 + ck * 8);
        }
    }
}

// ---------------- combined: stats (id%5==0) || cvt_rt (others), 2560 blocks ----------
// Interleave 1:4 so each CU's resident slots mix MFMA-heavy stats blocks with
// HBM-streaming rt blocks -> rt's ~30us of HBM traffic hides under stats' compute.
// Both branches share the 8.7 KB LDS union (R14 bodies verbatim).

__global__ __launch_bounds__(256) void stats_rt_kernel(const u16* __restrict__ q,
                                                       const u16* __restrict__ k,
                                                       float2* __restrict__ gso,
                                                       const float* __restrict__ r,
                                                       u16* __restrict__ rt) {
    __shared__ __align__(16) char shmem[64 * 68 * 2];   // 8704 B union

    int tid = threadIdx.x;
    int id = blockIdx.x;
    if (id % 5 == 0) {
        // ================= stats (512 blocks: ids 0,5,...,2555) =================
        int flat = id / 5;
        int sw = (flat & 7) * 64 + (flat >> 3);   // bijective XCD swizzle
        int b = sw >> 5;
        int c0 = (sw & 31) * 64;
        int lane = tid & 63, w = tid >> 6;
        int lr = lane & 15, lg = lane >> 4;
        const u16* qb = q + (size_t)b * NT * DIM;
        const u16* kb = k + (size_t)b * NC * DIM;
        const float A2 = 1.44269504f / 16.0f;

        bfx8 kf[4][8];
#pragma unroll
        for (int j = 0; j < 4; j++)
#pragma unroll
            for (int ks = 0; ks < 8; ks++)
                kf[j][ks] = *reinterpret_cast<const bfx8*>(kb + (size_t)(c0 + j * 16 + lr) * DIM + ks * 32 + lg * 8);

        float m_run[4], l_run[4];
#pragma unroll
        for (int j = 0; j < 4; j++) { m_run[j] = -1e30f; l_run[j] = 0.0f; }

#define LOADQ(dst, ts_) do {                                                        \
    const u16* qrow_ = qb + (size_t)((ts_) * 64 + w * 16 + lr) * DIM;               \
    _Pragma("unroll")                                                               \
    for (int ks_ = 0; ks_ < 8; ks_++)                                               \
        dst[ks_] = *reinterpret_cast<const bfx8*>(qrow_ + ks_ * 32 + lg * 8);       \
} while (0)

#define STEP(aq_) do {                                                              \
    f32x4 sacc[4] = {};                                                             \
    _Pragma("unroll")                                                               \
    for (int ks_ = 0; ks_ < 8; ks_++) {                                             \
        _Pragma("unroll")                                                           \
        for (int j_ = 0; j_ < 4; j_++)                                              \
            sacc[j_] = MFMA16(aq_[ks_], kf[j_][ks_], sacc[j_]);                     \
    }                                                                               \
    _Pragma("unroll")                                                               \
    for (int j_ = 0; j_ < 4; j_++) {                                                \
        f32x4 a_ = sacc[j_];                                                        \
        float mx_ = fmaxf(fmaxf(a_[0], a_[1]), fmaxf(a_[2], a_[3]));                \
        if (mx_ > m_run[j_] + 88.0f) {                                              \
            l_run[j_] *= exp2f((m_run[j_] - mx_) * A2);                             \
            m_run[j_] = mx_;                                                        \
        }                                                                           \
        float t_ = m_run[j_] * A2;                                                  \
        l_run[j_] += exp2f(fmaf(a_[0], A2, -t_)) + exp2f(fmaf(a_[1], A2, -t_))      \
                   + exp2f(fmaf(a_[2], A2, -t_)) + exp2f(fmaf(a_[3], A2, -t_));     \
    }                                                                               \
} while (0)

        bfx8 a0[8], a1[8];
        LOADQ(a0, 0);
        for (int ts = 0; ts < NT / 64; ts += 2) {
            LOADQ(a1, ts + 1);
            STEP(a0);
            if (ts + 2 < NT / 64) LOADQ(a0, ts + 2);
            STEP(a1);
        }
#undef LOADQ
#undef STEP

        // intra-wave combine across the 4 lane-groups, once
#pragma unroll
        for (int j = 0; j < 4; j++) {
            float m = m_run[j], l = l_run[j];
#pragma unroll
            for (int d = 16; d < 64; d <<= 1) {
                float mo = __shfl_xor(m, d);
                float lo = __shfl_xor(l, d);
                float mn = fmaxf(m, mo);
                l = l * exp2f((m - mn) * A2) + lo * exp2f((mo - mn) * A2);
                m = mn;
            }
            m_run[j] = m; l_run[j] = l;
        }

        float* sm = (float*)shmem;        // [4][64]
        float* sl = sm + 256;             // [4][64]
        if (lg == 0) {
#pragma unroll
            for (int j = 0; j < 4; j++) {
                sm[w * 64 + j * 16 + lr] = m_run[j];
                sl[w * 64 + j * 16 + lr] = l_run[j];
            }
        }
        __syncthreads();
        if (tid < 64) {
            float mf = sm[tid];
#pragma unroll
            for (int ww = 1; ww < 4; ww++) mf = fmaxf(mf, sm[ww * 64 + tid]);
            float lf = 0.0f;
#pragma unroll
            for (int ww = 0; ww < 4; ww++) lf += sl[ww * 64 + tid] * exp2f((sm[ww * 64 + tid] - mf) * A2);
            gso[(size_t)b * NC + c0 + tid] = make_float2(mf * A2, 1.0f / lf);
        }
    } else {
        // ================= cvt_rt (2048 blocks) =================
        int idx = id - id / 5 - 1;           // bijective onto [0, 2048)
        int b = idx >> 7;
        int d0 = ((idx >> 5) & 3) * 64;
        int c0 = (idx & 31) * 64;
        u16 (*t)[68] = (u16(*)[68])shmem;   // [64][68]
        const float* rb = r + (size_t)b * NC * DIM + d0;
        int cr = tid >> 4, df = (tid & 15) * 4;
#pragma unroll
        for (int p = 0; p < 4; p++) {
            int c = p * 16 + cr;
            float4 v = *reinterpret_cast<const float4*>(rb + (size_t)(c0 + c) * DIM + df);
            t[df + 0][c] = f2bf(v.x);
            t[df + 1][c] = f2bf(v.y);
            t[df + 2][c] = f2bf(v.z);
            t[df + 3][c] = f2bf(v.w);
        }
        __syncthreads();
        u16* rtb = rt + (size_t)b * DIM * NC;
        int dr = tid >> 3, cc = (tid & 7) * 8;
#pragma unroll
        for (int p = 0; p < 2; p++) {
            int d = p * 32 + dr;
            union { u16 u[8]; uint4 v; } pk;
#pragma unroll
            for (int j = 0; j < 8; j++) pk.u[j] = t[d][cc + j];
            *reinterpret_cast<uint4*>(rtb + (size_t)(d0 + d) * NC + c0 + cc) = pk.v;
        }
    }
}

// ---------------- pass 2: R4/R9-proven pipelined attention (127 us, FROZEN) ----------

__global__ __launch_bounds__(256, 2) void attn_kernel(const u16* __restrict__ q,
                                                      const u16* __restrict__ k,
                                                      const u16* __restrict__ rt,
                                                      const float2* __restrict__ gsg_,
                                                      float* __restrict__ out) {
    int flat = blockIdx.x;
    int sw = (flat & 7) * 64 + (flat >> 3);   // each XCD -> 2 batches (k+rt fit L2)
    int b = sw >> 5;
    int t0 = (sw & 31) * 64;
    int tid = threadIdx.x, lane = tid & 63, w = tid >> 6;
    int lr = lane & 15, lg = lane >> 4;
    const u16* qb = q + (size_t)b * NT * DIM;
    const u16* kb = k + (size_t)b * NC * DIM;
    const u16* rtb = rt + (size_t)b * DIM * NC;

    __shared__ float2 gs[NC];                       // 16 KB
    __shared__ __align__(16) u16 kt[2][32 * 256];   // 2 x 16 KB, swizzled K tiles
    __shared__ u16 pl[64][36];                      // P tile, 72B rows

    {
        const float2* gsg = gsg_ + (size_t)b * NC;
        for (int i = tid; i < NC; i += 256) gs[i] = gsg[i];
    }
    __syncthreads();

#define STAGE(nb, cc) do {                                                          \
    const u16* ksrc_ = kb + (size_t)(cc) * DIM;                                     \
    _Pragma("unroll")                                                               \
    for (int i_ = 0; i_ < 4; i_++) {                                                \
        int off_ = ((w * 4 + i_) << 10) + (lane << 4);                              \
        int row_ = off_ >> 9;                                                       \
        int ss_  = ((off_ >> 4) & 31) ^ (row_ & 7);                                 \
        const u16* g_ = ksrc_ + row_ * DIM + ss_ * 8;                               \
        __builtin_amdgcn_global_load_lds(                                           \
            (const __attribute__((address_space(1))) void*)g_,                      \
            (__attribute__((address_space(3))) void*)(&kt[nb][(w * 4 + i_) << 9]),  \
            16, 0, 0);                                                              \
    }                                                                               \
} while (0)

    // prologue: stage tile 0, prefetch rb for tile 0, hoist q
    STAGE(0, 0);
    __builtin_amdgcn_sched_barrier(0);
    bfx8 rb_c[4], rb_n[4];
#pragma unroll
    for (int nt = 0; nt < 4; nt++)
        rb_c[nt] = *reinterpret_cast<const bfx8*>(rtb + (size_t)(w * 64 + nt * 16 + lr) * NC + lg * 8);
    bfx8 aq[8];
#pragma unroll
    for (int ks = 0; ks < 8; ks++)
        aq[ks] = *reinterpret_cast<const bfx8*>(qb + (size_t)(t0 + w * 16 + lr) * DIM + ks * 32 + lg * 8);
    __builtin_amdgcn_sched_barrier(0);
    asm volatile("s_waitcnt vmcnt(12)");   // drain 4 stage issues (12 newer: 4 rb + 8 aq)
    __builtin_amdgcn_s_barrier();
    __builtin_amdgcn_sched_barrier(0);

    const float A = 1.44269504f / 16.0f;   // log2e * (1/sqrt(256))
    const int key = lr & 7;
    f32x4 acc[4][4] = {};
    int cur = 0;

    for (int c0 = 0; c0 < NC; c0 += 32) {
        const bool last = (c0 + 32 >= NC);
        if (!last) STAGE(cur ^ 1, c0 + 32);
        __builtin_amdgcn_sched_barrier(0);
        if (!last) {
#pragma unroll
            for (int nt = 0; nt < 4; nt++)
                rb_n[nt] = *reinterpret_cast<const bfx8*>(rtb + (size_t)(w * 64 + nt * 16 + lr) * NC + (c0 + 32) + lg * 8);
        }

        // S phase: read swizzled kt[cur], 16 MFMAs
        f32x4 s[2] = {};
        {
            const char* kc = (const char*)&kt[cur][0];
#pragma unroll
            for (int ks = 0; ks < 8; ks++) {
                int slot = (ks << 2) | lg;
                bfx8 k0 = *reinterpret_cast<const bfx8*>(kc + (lr << 9) + (((slot ^ key)) << 4));
                bfx8 k1 = *reinterpret_cast<const bfx8*>(kc + ((16 + lr) << 9) + (((slot ^ key)) << 4));
                s[0] = MFMA16(aq[ks], k0, s[0]);
                s[1] = MFMA16(aq[ks], k1, s[1]);
            }
        }
        // P = exp2(S*A - m') * invl -> LDS
#pragma unroll
        for (int j = 0; j < 2; j++) {
            float2 g = gs[c0 + j * 16 + lr];
#pragma unroll
            for (int r = 0; r < 4; r++) {
                float p = exp2f(fmaf(s[j][r], A, -g.x)) * g.y;
                __bf16 h = (__bf16)p;
                pl[w * 16 + lg * 4 + r][j * 16 + lr] = *(u16*)&h;
            }
        }
        __builtin_amdgcn_sched_barrier(0);
        asm volatile("s_waitcnt lgkmcnt(0)");
        __builtin_amdgcn_s_barrier();
        __builtin_amdgcn_sched_barrier(0);

        // PV phase
#pragma unroll
        for (int mt = 0; mt < 4; mt++) {
            bfx8a pa = *reinterpret_cast<const bfx8a*>((const char*)pl + (mt * 16 + lr) * 72 + lg * 16);
#pragma unroll
            for (int nt = 0; nt < 4; nt++)
                acc[mt][nt] = MFMA16((bfx8)pa, rb_c[nt], acc[mt][nt]);
        }

        __builtin_amdgcn_sched_barrier(0);
        asm volatile("s_waitcnt vmcnt(4) lgkmcnt(0)");
        __builtin_amdgcn_s_barrier();
        __builtin_amdgcn_sched_barrier(0);

#pragma unroll
        for (int nt = 0; nt < 4; nt++) rb_c[nt] = rb_n[nt];
        cur ^= 1;
    }
#undef STAGE

    float* ob = out + (size_t)b * NT * DIM;
#pragma unroll
    for (int nt = 0; nt < 4; nt++) {
        int col = w * 64 + nt * 16 + lr;
#pragma unroll
        for (int mt = 0; mt < 4; mt++) {
            int rowb = t0 + mt * 16 + lg * 4;
#pragma unroll
            for (int r = 0; r < 4; r++)
                ob[(size_t)(rowb + r) * DIM + col] = acc[mt][nt][r];
        }
    }
}

// ---------------- launch ----------------

extern "C" void kernel_launch(void* const* d_in, const int* in_sizes, int n_in,
                              void* d_out, int out_size, void* d_ws, size_t ws_size,
                              hipStream_t stream) {
    const float* xc  = (const float*)d_in[0];
    const float* xt  = (const float*)d_in[1];
    const float* ri  = (const float*)d_in[2];
    const float* qw1 = (const float*)d_in[3];  const float* qb1 = (const float*)d_in[4];
    const float* qw2 = (const float*)d_in[5];  const float* qb2 = (const float*)d_in[6];
    const float* qw3 = (const float*)d_in[7];  const float* qb3 = (const float*)d_in[8];
    const float* kw1 = (const float*)d_in[9];  const float* kb1 = (const float*)d_in[10];
    const float* kw2 = (const float*)d_in[11]; const float* kb2 = (const float*)d_in[12];
    const float* kw3 = (const float*)d_in[13]; const float* kb3 = (const float*)d_in[14];

    if (ws_size < ((size_t)66 << 20)) return;  // need ~50 MB

    char* ws = (char*)d_ws;
    u16* q   = (u16*)(ws);                        // 16 MB q bf16
    u16* kk  = (u16*)(ws + ((size_t)16 << 20));   // 16 MB k bf16
    u16* rt  = (u16*)(ws + ((size_t)32 << 20));   // 16 MB rt bf16
    float2* gsb = (float2*)(ws + ((size_t)48 << 20));          // 256 KB col stats
    u16* wbuf = (u16*)(ws + ((size_t)48 << 20) + (512 << 10)); // 640 KB weights
    u16* qw1t = wbuf;
    u16* qw2t = qw1t + 32768;
    u16* qw3t = qw2t + 65536;
    u16* kw1t = qw3t + 65536;
    u16* kw2t = kw1t + 32768;
    u16* kw3t = kw2t + 65536;

    // weights -> transposed bf16 (one launch)
    cvt_w_all<<<dim3(1280), 256, 0, stream>>>(qw1, qw2, qw3, kw1, kw2, kw3,
                                              qw1t, qw2t, qw3t, kw1t, kw2t, kw3t);

    // fused 3-layer MLP, both paths, 64-row tiles (standalone, R14-proven)
    mlp_fused<<<dim3(512, 2), 256, 0, stream>>>(xt, xc,
                                                qw1t, kw1t, qb1, kb1,
                                                qw2t, kw2t, qb2, kb2,
                                                qw3t, kw3t, qb3, kb3,
                                                q, kk);

    // stats (512) || cvt_rt (2048), interleaved 1:4 for true co-residency
    stats_rt_kernel<<<dim3(2560), 256, 0, stream>>>(q, kk, gsb, ri, rt);

    // pass 2: attention output
    attn_kernel<<<dim3(512), 256, 0, stream>>>(q, kk, rt, gsb, (float*)d_out);
}

// Round 17
// 249.323 us; speedup vs baseline: 1.1137x; 1.1137x over previous
//
#include <hip/hip_runtime.h>

#define BB 16
#define NT 2048
#define NC 2048
#define DIM 256
#define INDIM 128

typedef unsigned short u16;
typedef __bf16 bfx8 __attribute__((ext_vector_type(8)));
typedef __bf16 bfx8a __attribute__((ext_vector_type(8), aligned(8)));
typedef float f32x4 __attribute__((ext_vector_type(4)));

__device__ __forceinline__ u16 f2bf(float f) {
    union { float f; unsigned u; } v; v.f = f;
    return (u16)((v.u + 0x7FFFu + ((v.u >> 16) & 1u)) >> 16);
}

#define MFMA16(a, b, c) __builtin_amdgcn_mfma_f32_16x16x32_bf16((a), (b), (c), 0, 0, 0)

// ---------------- converts ----------------

// all six weight transposes in ONE launch: w[K][256] fp32 -> wt [256][K] bf16
__global__ void cvt_w_all(const float* __restrict__ w0, const float* __restrict__ w1,
                          const float* __restrict__ w2, const float* __restrict__ w3,
                          const float* __restrict__ w4, const float* __restrict__ w5,
                          u16* __restrict__ o0, u16* __restrict__ o1, u16* __restrict__ o2,
                          u16* __restrict__ o3, u16* __restrict__ o4, u16* __restrict__ o5) {
    int bx = blockIdx.x;
    const float* src; u16* dst; int K, base;
    if (bx < 128)       { src = w0; dst = o0; K = 128; base = 0; }
    else if (bx < 384)  { src = w1; dst = o1; K = 256; base = 128; }
    else if (bx < 640)  { src = w2; dst = o2; K = 256; base = 384; }
    else if (bx < 768)  { src = w3; dst = o3; K = 128; base = 640; }
    else if (bx < 1024) { src = w4; dst = o4; K = 256; base = 768; }
    else                { src = w5; dst = o5; K = 256; base = 1024; }
    int idx = (bx - base) * 256 + threadIdx.x;
    int n = idx / K, k = idx - n * K;
    dst[idx] = f2bf(src[k * 256 + n]);
}

// ---------------- fused 3-layer MLP, 64-row tiles (R11/R14-proven, standalone) --------

__global__ __launch_bounds__(256) void mlp_fused(const float* __restrict__ xq, const float* __restrict__ xk,
                                                 const u16* __restrict__ W1q, const u16* __restrict__ W1k,
                                                 const float* __restrict__ b1q, const float* __restrict__ b1k,
                                                 const u16* __restrict__ W2q, const u16* __restrict__ W2k,
                                                 const float* __restrict__ b2q, const float* __restrict__ b2k,
                                                 const u16* __restrict__ W3q, const u16* __restrict__ W3k,
                                                 const float* __restrict__ b3q, const float* __restrict__ b3k,
                                                 u16* __restrict__ oq, u16* __restrict__ ok) {
    __shared__ __align__(16) char lds[65536];
    char* h1 = lds;            // [64][256] bf16, 512 B rows, swizzled; later: epilogue tile
    char* xa = lds + 32768;    // [64][128] bf16, 256 B rows, swizzled
    char* h2 = lds + 32768;    // [64][256] bf16, swizzled (overlays xa after it's dead)

    int tid = threadIdx.x, lane = tid & 63, w = tid >> 6;
    int lr = lane & 15, lg = lane >> 4;
    int m0 = blockIdx.x * 64;
    bool isq = (blockIdx.y == 0);
    const float* X = (isq ? xq : xk) + (size_t)m0 * INDIM;
    const u16* W1 = isq ? W1q : W1k;  const float* b1 = isq ? b1q : b1k;
    const u16* W2 = isq ? W2q : W2k;  const float* b2 = isq ? b2q : b2k;
    const u16* W3 = isq ? W3q : W3k;  const float* b3 = isq ? b3q : b3k;
    u16* C = (isq ? oq : ok) + (size_t)m0 * 256;

    // stage x: 64x128 fp32 -> bf16 swizzled (4 chunks of 16 B per thread)
#pragma unroll
    for (int j = 0; j < 4; j++) {
        int bo = (j * 256 + tid) * 16;
        int row = bo >> 8;                        // 256 B rows
        int ir = bo & 255;
        const float* src = X + (size_t)row * INDIM + (ir >> 1);
        float4 f0 = *reinterpret_cast<const float4*>(src);
        float4 f1 = *reinterpret_cast<const float4*>(src + 4);
        union { u16 u[8]; uint4 v; } pk;
        pk.u[0] = f2bf(f0.x); pk.u[1] = f2bf(f0.y); pk.u[2] = f2bf(f0.z); pk.u[3] = f2bf(f0.w);
        pk.u[4] = f2bf(f1.x); pk.u[5] = f2bf(f1.y); pk.u[6] = f2bf(f1.z); pk.u[7] = f2bf(f1.w);
        *reinterpret_cast<uint4*>(xa + row * 256 + (ir ^ ((row & 7) << 4))) = pk.v;
    }
    __syncthreads();

    int n0 = w * 64;
    const int key = (lr & 7) << 4;

    // ---- GEMM1: h1 = relu(x @ W1^T + b1), K=128 ----
    {
        f32x4 acc[4][4] = {};
#pragma unroll
        for (int ks = 0; ks < 4; ks++) {
            bfx8 b[4];
#pragma unroll
            for (int nt = 0; nt < 4; nt++)
                b[nt] = *reinterpret_cast<const bfx8*>(W1 + (size_t)(n0 + nt * 16 + lr) * 128 + ks * 32 + lg * 8);
#pragma unroll
            for (int mt = 0; mt < 4; mt++) {
                bfx8 a = *reinterpret_cast<const bfx8*>(xa + (mt * 16 + lr) * 256 + ((ks * 64 + lg * 16) ^ key));
#pragma unroll
                for (int nt = 0; nt < 4; nt++)
                    acc[mt][nt] = MFMA16(a, b[nt], acc[mt][nt]);
            }
        }
#pragma unroll
        for (int nt = 0; nt < 4; nt++) {
            int col = n0 + nt * 16 + lr;
            float bv = b1[col];
#pragma unroll
            for (int mt = 0; mt < 4; mt++) {
#pragma unroll
                for (int r2 = 0; r2 < 4; r2++) {
                    int row = mt * 16 + lg * 4 + r2;
                    float v = fmaxf(acc[mt][nt][r2] + bv, 0.0f);
                    *(u16*)(h1 + row * 512 + ((col * 2) ^ ((row & 7) << 4))) = f2bf(v);
                }
            }
        }
    }
    __syncthreads();

    // ---- GEMM2: h2 = relu(h1 @ W2^T + b2), K=256 ----
    {
        f32x4 acc[4][4] = {};
#pragma unroll
        for (int ks = 0; ks < 8; ks++) {
            bfx8 b[4];
#pragma unroll
            for (int nt = 0; nt < 4; nt++)
                b[nt] = *reinterpret_cast<const bfx8*>(W2 + (size_t)(n0 + nt * 16 + lr) * 256 + ks * 32 + lg * 8);
#pragma unroll
            for (int mt = 0; mt < 4; mt++) {
                bfx8 a = *reinterpret_cast<const bfx8*>(h1 + (mt * 16 + lr) * 512 + ((ks * 64 + lg * 16) ^ key));
#pragma unroll
                for (int nt = 0; nt < 4; nt++)
                    acc[mt][nt] = MFMA16(a, b[nt], acc[mt][nt]);
            }
        }
#pragma unroll
        for (int nt = 0; nt < 4; nt++) {
            int col = n0 + nt * 16 + lr;
            float bv = b2[col];
#pragma unroll
            for (int mt = 0; mt < 4; mt++) {
#pragma unroll
                for (int r2 = 0; r2 < 4; r2++) {
                    int row = mt * 16 + lg * 4 + r2;
                    float v = fmaxf(acc[mt][nt][r2] + bv, 0.0f);
                    *(u16*)(h2 + row * 512 + ((col * 2) ^ ((row & 7) << 4))) = f2bf(v);
                }
            }
        }
    }
    __syncthreads();

    // ---- GEMM3: out = h2 @ W3^T + b3, K=256; epilogue via LDS (h1 dead) ----
    {
        f32x4 acc[4][4] = {};
#pragma unroll
        for (int ks = 0; ks < 8; ks++) {
            bfx8 b[4];
#pragma unroll
            for (int nt = 0; nt < 4; nt++)
                b[nt] = *reinterpret_cast<const bfx8*>(W3 + (size_t)(n0 + nt * 16 + lr) * 256 + ks * 32 + lg * 8);
#pragma unroll
            for (int mt = 0; mt < 4; mt++) {
                bfx8 a = *reinterpret_cast<const bfx8*>(h2 + (mt * 16 + lr) * 512 + ((ks * 64 + lg * 16) ^ key));
#pragma unroll
                for (int nt = 0; nt < 4; nt++)
                    acc[mt][nt] = MFMA16(a, b[nt], acc[mt][nt]);
            }
        }
        u16* ot = (u16*)h1;   // [64][256] staging for coalesced store
#pragma unroll
        for (int nt = 0; nt < 4; nt++) {
            int col = n0 + nt * 16 + lr;
            float bv = b3[col];
#pragma unroll
            for (int mt = 0; mt < 4; mt++) {
#pragma unroll
                for (int r2 = 0; r2 < 4; r2++) {
                    int row = mt * 16 + lg * 4 + r2;
                    ot[row * 256 + col] = f2bf(acc[mt][nt][r2] + bv);
                }
            }
        }
        __syncthreads();
#pragma unroll
        for (int p = 0; p < 8; p++) {
            int idx = p * 256 + tid;           // 2048 chunks of 16 B
            int row = idx >> 5, ck = idx & 31;
            *reinterpret_cast<uint4*>(C + (size_t)row * 256 + ck * 8) =
                *reinterpret_cast<const uint4*>(ot + row * 256 + ck * 8);
        }
    }
}

// ---------------- combined: cvt_rt (ids 0-2047, FIRST) || stats (ids 2048-2559) --------
// rt blocks are short HBM-streamers: they flood the machine and drain in ~4 quick
// residency waves; stats blocks backfill within ~15us and then run at full residency
// with rt's traffic mostly finished (cleaner L2 for q/k). Bodies = R14 verbatim.

__global__ __launch_bounds__(256) void stats_rt_kernel(const u16* __restrict__ q,
                                                       const u16* __restrict__ k,
                                                       float2* __restrict__ gso,
                                                       const float* __restrict__ r,
                                                       u16* __restrict__ rt) {
    __shared__ __align__(16) char shmem[64 * 68 * 2];   // 8704 B union

    int tid = threadIdx.x;
    int id = blockIdx.x;
    if (id >= 2048) {
        // ================= stats (512 blocks: ids 2048-2559) =================
        int flat = id - 2048;
        int sw = (flat & 7) * 64 + (flat >> 3);   // bijective XCD swizzle
        int b = sw >> 5;
        int c0 = (sw & 31) * 64;
        int lane = tid & 63, w = tid >> 6;
        int lr = lane & 15, lg = lane >> 4;
        const u16* qb = q + (size_t)b * NT * DIM;
        const u16* kb = k + (size_t)b * NC * DIM;
        const float A2 = 1.44269504f / 16.0f;

        bfx8 kf[4][8];
#pragma unroll
        for (int j = 0; j < 4; j++)
#pragma unroll
            for (int ks = 0; ks < 8; ks++)
                kf[j][ks] = *reinterpret_cast<const bfx8*>(kb + (size_t)(c0 + j * 16 + lr) * DIM + ks * 32 + lg * 8);

        float m_run[4], l_run[4];
#pragma unroll
        for (int j = 0; j < 4; j++) { m_run[j] = -1e30f; l_run[j] = 0.0f; }

#define LOADQ(dst, ts_) do {                                                        \
    const u16* qrow_ = qb + (size_t)((ts_) * 64 + w * 16 + lr) * DIM;               \
    _Pragma("unroll")                                                               \
    for (int ks_ = 0; ks_ < 8; ks_++)                                               \
        dst[ks_] = *reinterpret_cast<const bfx8*>(qrow_ + ks_ * 32 + lg * 8);       \
} while (0)

#define STEP(aq_) do {                                                              \
    f32x4 sacc[4] = {};                                                             \
    _Pragma("unroll")                                                               \
    for (int ks_ = 0; ks_ < 8; ks_++) {                                             \
        _Pragma("unroll")                                                           \
        for (int j_ = 0; j_ < 4; j_++)                                              \
            sacc[j_] = MFMA16(aq_[ks_], kf[j_][ks_], sacc[j_]);                     \
    }                                                                               \
    _Pragma("unroll")                                                               \
    for (int j_ = 0; j_ < 4; j_++) {                                                \
        f32x4 a_ = sacc[j_];                                                        \
        float mx_ = fmaxf(fmaxf(a_[0], a_[1]), fmaxf(a_[2], a_[3]));                \
        if (mx_ > m_run[j_] + 88.0f) {                                              \
            l_run[j_] *= exp2f((m_run[j_] - mx_) * A2);                             \
            m_run[j_] = mx_;                                                        \
        }                                                                           \
        float t_ = m_run[j_] * A2;                                                  \
        l_run[j_] += exp2f(fmaf(a_[0], A2, -t_)) + exp2f(fmaf(a_[1], A2, -t_))      \
                   + exp2f(fmaf(a_[2], A2, -t_)) + exp2f(fmaf(a_[3], A2, -t_));     \
    }                                                                               \
} while (0)

        bfx8 a0[8], a1[8];
        LOADQ(a0, 0);
        for (int ts = 0; ts < NT / 64; ts += 2) {
            LOADQ(a1, ts + 1);
            STEP(a0);
            if (ts + 2 < NT / 64) LOADQ(a0, ts + 2);
            STEP(a1);
        }
#undef LOADQ
#undef STEP

        // intra-wave combine across the 4 lane-groups, once
#pragma unroll
        for (int j = 0; j < 4; j++) {
            float m = m_run[j], l = l_run[j];
#pragma unroll
            for (int d = 16; d < 64; d <<= 1) {
                float mo = __shfl_xor(m, d);
                float lo = __shfl_xor(l, d);
                float mn = fmaxf(m, mo);
                l = l * exp2f((m - mn) * A2) + lo * exp2f((mo - mn) * A2);
                m = mn;
            }
            m_run[j] = m; l_run[j] = l;
        }

        float* sm = (float*)shmem;        // [4][64]
        float* sl = sm + 256;             // [4][64]
        if (lg == 0) {
#pragma unroll
            for (int j = 0; j < 4; j++) {
                sm[w * 64 + j * 16 + lr] = m_run[j];
                sl[w * 64 + j * 16 + lr] = l_run[j];
            }
        }
        __syncthreads();
        if (tid < 64) {
            float mf = sm[tid];
#pragma unroll
            for (int ww = 1; ww < 4; ww++) mf = fmaxf(mf, sm[ww * 64 + tid]);
            float lf = 0.0f;
#pragma unroll
            for (int ww = 0; ww < 4; ww++) lf += sl[ww * 64 + tid] * exp2f((sm[ww * 64 + tid] - mf) * A2);
            gso[(size_t)b * NC + c0 + tid] = make_float2(mf * A2, 1.0f / lf);
        }
    } else {
        // ================= cvt_rt (2048 blocks: ids 0-2047) =================
        int idx = id;
        int b = idx >> 7;
        int d0 = ((idx >> 5) & 3) * 64;
        int c0 = (idx & 31) * 64;
        u16 (*t)[68] = (u16(*)[68])shmem;   // [64][68]
        const float* rb = r + (size_t)b * NC * DIM + d0;
        int cr = tid >> 4, df = (tid & 15) * 4;
#pragma unroll
        for (int p = 0; p < 4; p++) {
            int c = p * 16 + cr;
            float4 v = *reinterpret_cast<const float4*>(rb + (size_t)(c0 + c) * DIM + df);
            t[df + 0][c] = f2bf(v.x);
            t[df + 1][c] = f2bf(v.y);
            t[df + 2][c] = f2bf(v.z);
            t[df + 3][c] = f2bf(v.w);
        }
        __syncthreads();
        u16* rtb = rt + (size_t)b * DIM * NC;
        int dr = tid >> 3, cc = (tid & 7) * 8;
#pragma unroll
        for (int p = 0; p < 2; p++) {
            int d = p * 32 + dr;
            union { u16 u[8]; uint4 v; } pk;
#pragma unroll
            for (int j = 0; j < 8; j++) pk.u[j] = t[d][cc + j];
            *reinterpret_cast<uint4*>(rtb + (size_t)(d0 + d) * NC + c0 + cc) = pk.v;
        }
    }
}

// ---------------- pass 2: R4/R9-proven pipelined attention (127 us, FROZEN) ----------

__global__ __launch_bounds__(256, 2) void attn_kernel(const u16* __restrict__ q,
                                                      const u16* __restrict__ k,
                                                      const u16* __restrict__ rt,
                                                      const float2* __restrict__ gsg_,
                                                      float* __restrict__ out) {
    int flat = blockIdx.x;
    int sw = (flat & 7) * 64 + (flat >> 3);   // each XCD -> 2 batches (k+rt fit L2)
    int b = sw >> 5;
    int t0 = (sw & 31) * 64;
    int tid = threadIdx.x, lane = tid & 63, w = tid >> 6;
    int lr = lane & 15, lg = lane >> 4;
    const u16* qb = q + (size_t)b * NT * DIM;
    const u16* kb = k + (size_t)b * NC * DIM;
    const u16* rtb = rt + (size_t)b * DIM * NC;

    __shared__ float2 gs[NC];                       // 16 KB
    __shared__ __align__(16) u16 kt[2][32 * 256];   // 2 x 16 KB, swizzled K tiles
    __shared__ u16 pl[64][36];                      // P tile, 72B rows

    {
        const float2* gsg = gsg_ + (size_t)b * NC;
        for (int i = tid; i < NC; i += 256) gs[i] = gsg[i];
    }
    __syncthreads();

#define STAGE(nb, cc) do {                                                          \
    const u16* ksrc_ = kb + (size_t)(cc) * DIM;                                     \
    _Pragma("unroll")                                                               \
    for (int i_ = 0; i_ < 4; i_++) {                                                \
        int off_ = ((w * 4 + i_) << 10) + (lane << 4);                              \
        int row_ = off_ >> 9;                                                       \
        int ss_  = ((off_ >> 4) & 31) ^ (row_ & 7);                                 \
        const u16* g_ = ksrc_ + row_ * DIM + ss_ * 8;                               \
        __builtin_amdgcn_global_load_lds(                                           \
            (const __attribute__((address_space(1))) void*)g_,                      \
            (__attribute__((address_space(3))) void*)(&kt[nb][(w * 4 + i_) << 9]),  \
            16, 0, 0);                                                              \
    }                                                                               \
} while (0)

    // prologue: stage tile 0, prefetch rb for tile 0, hoist q
    STAGE(0, 0);
    __builtin_amdgcn_sched_barrier(0);
    bfx8 rb_c[4], rb_n[4];
#pragma unroll
    for (int nt = 0; nt < 4; nt++)
        rb_c[nt] = *reinterpret_cast<const bfx8*>(rtb + (size_t)(w * 64 + nt * 16 + lr) * NC + lg * 8);
    bfx8 aq[8];
#pragma unroll
    for (int ks = 0; ks < 8; ks++)
        aq[ks] = *reinterpret_cast<const bfx8*>(qb + (size_t)(t0 + w * 16 + lr) * DIM + ks * 32 + lg * 8);
    __builtin_amdgcn_sched_barrier(0);
    asm volatile("s_waitcnt vmcnt(12)");   // drain 4 stage issues (12 newer: 4 rb + 8 aq)
    __builtin_amdgcn_s_barrier();
    __builtin_amdgcn_sched_barrier(0);

    const float A = 1.44269504f / 16.0f;   // log2e * (1/sqrt(256))
    const int key = lr & 7;
    f32x4 acc[4][4] = {};
    int cur = 0;

    for (int c0 = 0; c0 < NC; c0 += 32) {
        const bool last = (c0 + 32 >= NC);
        if (!last) STAGE(cur ^ 1, c0 + 32);
        __builtin_amdgcn_sched_barrier(0);
        if (!last) {
#pragma unroll
            for (int nt = 0; nt < 4; nt++)
                rb_n[nt] = *reinterpret_cast<const bfx8*>(rtb + (size_t)(w * 64 + nt * 16 + lr) * NC + (c0 + 32) + lg * 8);
        }

        // S phase: read swizzled kt[cur], 16 MFMAs
        f32x4 s[2] = {};
        {
            const char* kc = (const char*)&kt[cur][0];
#pragma unroll
            for (int ks = 0; ks < 8; ks++) {
                int slot = (ks << 2) | lg;
                bfx8 k0 = *reinterpret_cast<const bfx8*>(kc + (lr << 9) + (((slot ^ key)) << 4));
                bfx8 k1 = *reinterpret_cast<const bfx8*>(kc + ((16 + lr) << 9) + (((slot ^ key)) << 4));
                s[0] = MFMA16(aq[ks], k0, s[0]);
                s[1] = MFMA16(aq[ks], k1, s[1]);
            }
        }
        // P = exp2(S*A - m') * invl -> LDS
#pragma unroll
        for (int j = 0; j < 2; j++) {
            float2 g = gs[c0 + j * 16 + lr];
#pragma unroll
            for (int r = 0; r < 4; r++) {
                float p = exp2f(fmaf(s[j][r], A, -g.x)) * g.y;
                __bf16 h = (__bf16)p;
                pl[w * 16 + lg * 4 + r][j * 16 + lr] = *(u16*)&h;
            }
        }
        __builtin_amdgcn_sched_barrier(0);
        asm volatile("s_waitcnt lgkmcnt(0)");
        __builtin_amdgcn_s_barrier();
        __builtin_amdgcn_sched_barrier(0);

        // PV phase
#pragma unroll
        for (int mt = 0; mt < 4; mt++) {
            bfx8a pa = *reinterpret_cast<const bfx8a*>((const char*)pl + (mt * 16 + lr) * 72 + lg * 16);
#pragma unroll
            for (int nt = 0; nt < 4; nt++)
                acc[mt][nt] = MFMA16((bfx8)pa, rb_c[nt], acc[mt][nt]);
        }

        __builtin_amdgcn_sched_barrier(0);
        asm volatile("s_waitcnt vmcnt(4) lgkmcnt(0)");
        __builtin_amdgcn_s_barrier();
        __builtin_amdgcn_sched_barrier(0);

#pragma unroll
        for (int nt = 0; nt < 4; nt++) rb_c[nt] = rb_n[nt];
        cur ^= 1;
    }
#undef STAGE

    float* ob = out + (size_t)b * NT * DIM;
#pragma unroll
    for (int nt = 0; nt < 4; nt++) {
        int col = w * 64 + nt * 16 + lr;
#pragma unroll
        for (int mt = 0; mt < 4; mt++) {
            int rowb = t0 + mt * 16 + lg * 4;
#pragma unroll
            for (int r = 0; r < 4; r++)
                ob[(size_t)(rowb + r) * DIM + col] = acc[mt][nt][r];
        }
    }
}

// ---------------- launch ----------------

extern "C" void kernel_launch(void* const* d_in, const int* in_sizes, int n_in,
                              void* d_out, int out_size, void* d_ws, size_t ws_size,
                              hipStream_t stream) {
    const float* xc  = (const float*)d_in[0];
    const float* xt  = (const float*)d_in[1];
    const float* ri  = (const float*)d_in[2];
    const float* qw1 = (const float*)d_in[3];  const float* qb1 = (const float*)d_in[4];
    const float* qw2 = (const float*)d_in[5];  const float* qb2 = (const float*)d_in[6];
    const float* qw3 = (const float*)d_in[7];  const float* qb3 = (const float*)d_in[8];
    const float* kw1 = (const float*)d_in[9];  const float* kb1 = (const float*)d_in[10];
    const float* kw2 = (const float*)d_in[11]; const float* kb2 = (const float*)d_in[12];
    const float* kw3 = (const float*)d_in[13]; const float* kb3 = (const float*)d_in[14];

    if (ws_size < ((size_t)66 << 20)) return;  // need ~50 MB

    char* ws = (char*)d_ws;
    u16* q   = (u16*)(ws);                        // 16 MB q bf16
    u16* kk  = (u16*)(ws + ((size_t)16 << 20));   // 16 MB k bf16
    u16* rt  = (u16*)(ws + ((size_t)32 << 20));   // 16 MB rt bf16
    float2* gsb = (float2*)(ws + ((size_t)48 << 20));          // 256 KB col stats
    u16* wbuf = (u16*)(ws + ((size_t)48 << 20) + (512 << 10)); // 640 KB weights
    u16* qw1t = wbuf;
    u16* qw2t = qw1t + 32768;
    u16* qw3t = qw2t + 65536;
    u16* kw1t = qw3t + 65536;
    u16* kw2t = kw1t + 32768;
    u16* kw3t = kw2t + 65536;

    // weights -> transposed bf16 (one launch)
    cvt_w_all<<<dim3(1280), 256, 0, stream>>>(qw1, qw2, qw3, kw1, kw2, kw3,
                                              qw1t, qw2t, qw3t, kw1t, kw2t, kw3t);

    // fused 3-layer MLP, both paths, 64-row tiles (standalone, R14-proven)
    mlp_fused<<<dim3(512, 2), 256, 0, stream>>>(xt, xc,
                                                qw1t, kw1t, qb1, kb1,
                                                qw2t, kw2t, qb2, kb2,
                                                qw3t, kw3t, qb3, kb3,
                                                q, kk);

    // cvt_rt (2048, dispatched first) || stats (512, backfill at full residency)
    stats_rt_kernel<<<dim3(2560), 256, 0, stream>>>(q, kk, gsb, ri, rt);

    // pass 2: attention output
    attn_kernel<<<dim3(512), 256, 0, stream>>>(q, kk, rt, gsb, (float*)d_out);
}

// Round 18
// 246.326 us; speedup vs baseline: 1.1272x; 1.0122x over previous
//
#include <hip/hip_runtime.h>

#define BB 16
#define NT 2048
#define NC 2048
#define DIM 256
#define INDIM 128

typedef unsigned short u16;
typedef __bf16 bfx8 __attribute__((ext_vector_type(8)));
typedef __bf16 bfx8a __attribute__((ext_vector_type(8), aligned(8)));
typedef float f32x4 __attribute__((ext_vector_type(4)));

__device__ __forceinline__ u16 f2bf(float f) {
    union { float f; unsigned u; } v; v.f = f;
    return (u16)((v.u + 0x7FFFu + ((v.u >> 16) & 1u)) >> 16);
}

#define MFMA16(a, b, c) __builtin_amdgcn_mfma_f32_16x16x32_bf16((a), (b), (c), 0, 0, 0)

// ---------------- converts ----------------

// all six weight transposes in ONE launch: w[K][256] fp32 -> wt [256][K] bf16
__global__ void cvt_w_all(const float* __restrict__ w0, const float* __restrict__ w1,
                          const float* __restrict__ w2, const float* __restrict__ w3,
                          const float* __restrict__ w4, const float* __restrict__ w5,
                          u16* __restrict__ o0, u16* __restrict__ o1, u16* __restrict__ o2,
                          u16* __restrict__ o3, u16* __restrict__ o4, u16* __restrict__ o5) {
    int bx = blockIdx.x;
    const float* src; u16* dst; int K, base;
    if (bx < 128)       { src = w0; dst = o0; K = 128; base = 0; }
    else if (bx < 384)  { src = w1; dst = o1; K = 256; base = 128; }
    else if (bx < 640)  { src = w2; dst = o2; K = 256; base = 384; }
    else if (bx < 768)  { src = w3; dst = o3; K = 128; base = 640; }
    else if (bx < 1024) { src = w4; dst = o4; K = 256; base = 768; }
    else                { src = w5; dst = o5; K = 256; base = 1024; }
    int idx = (bx - base) * 256 + threadIdx.x;
    int n = idx / K, k = idx - n * K;
    dst[idx] = f2bf(src[k * 256 + n]);
}

// ---------------- fused 3-layer MLP, 64-row tiles (R11/R14-proven, standalone) --------

__global__ __launch_bounds__(256) void mlp_fused(const float* __restrict__ xq, const float* __restrict__ xk,
                                                 const u16* __restrict__ W1q, const u16* __restrict__ W1k,
                                                 const float* __restrict__ b1q, const float* __restrict__ b1k,
                                                 const u16* __restrict__ W2q, const u16* __restrict__ W2k,
                                                 const float* __restrict__ b2q, const float* __restrict__ b2k,
                                                 const u16* __restrict__ W3q, const u16* __restrict__ W3k,
                                                 const float* __restrict__ b3q, const float* __restrict__ b3k,
                                                 u16* __restrict__ oq, u16* __restrict__ ok) {
    __shared__ __align__(16) char lds[65536];
    char* h1 = lds;            // [64][256] bf16, 512 B rows, swizzled; later: epilogue tile
    char* xa = lds + 32768;    // [64][128] bf16, 256 B rows, swizzled
    char* h2 = lds + 32768;    // [64][256] bf16, swizzled (overlays xa after it's dead)

    int tid = threadIdx.x, lane = tid & 63, w = tid >> 6;
    int lr = lane & 15, lg = lane >> 4;
    int m0 = blockIdx.x * 64;
    bool isq = (blockIdx.y == 0);
    const float* X = (isq ? xq : xk) + (size_t)m0 * INDIM;
    const u16* W1 = isq ? W1q : W1k;  const float* b1 = isq ? b1q : b1k;
    const u16* W2 = isq ? W2q : W2k;  const float* b2 = isq ? b2q : b2k;
    const u16* W3 = isq ? W3q : W3k;  const float* b3 = isq ? b3q : b3k;
    u16* C = (isq ? oq : ok) + (size_t)m0 * 256;

    // stage x: 64x128 fp32 -> bf16 swizzled (4 chunks of 16 B per thread)
#pragma unroll
    for (int j = 0; j < 4; j++) {
        int bo = (j * 256 + tid) * 16;
        int row = bo >> 8;                        // 256 B rows
        int ir = bo & 255;
        const float* src = X + (size_t)row * INDIM + (ir >> 1);
        float4 f0 = *reinterpret_cast<const float4*>(src);
        float4 f1 = *reinterpret_cast<const float4*>(src + 4);
        union { u16 u[8]; uint4 v; } pk;
        pk.u[0] = f2bf(f0.x); pk.u[1] = f2bf(f0.y); pk.u[2] = f2bf(f0.z); pk.u[3] = f2bf(f0.w);
        pk.u[4] = f2bf(f1.x); pk.u[5] = f2bf(f1.y); pk.u[6] = f2bf(f1.z); pk.u[7] = f2bf(f1.w);
        *reinterpret_cast<uint4*>(xa + row * 256 + (ir ^ ((row & 7) << 4))) = pk.v;
    }
    __syncthreads();

    int n0 = w * 64;
    const int key = (lr & 7) << 4;

    // ---- GEMM1: h1 = relu(x @ W1^T + b1), K=128 ----
    {
        f32x4 acc[4][4] = {};
#pragma unroll
        for (int ks = 0; ks < 4; ks++) {
            bfx8 b[4];
#pragma unroll
            for (int nt = 0; nt < 4; nt++)
                b[nt] = *reinterpret_cast<const bfx8*>(W1 + (size_t)(n0 + nt * 16 + lr) * 128 + ks * 32 + lg * 8);
#pragma unroll
            for (int mt = 0; mt < 4; mt++) {
                bfx8 a = *reinterpret_cast<const bfx8*>(xa + (mt * 16 + lr) * 256 + ((ks * 64 + lg * 16) ^ key));
#pragma unroll
                for (int nt = 0; nt < 4; nt++)
                    acc[mt][nt] = MFMA16(a, b[nt], acc[mt][nt]);
            }
        }
#pragma unroll
        for (int nt = 0; nt < 4; nt++) {
            int col = n0 + nt * 16 + lr;
            float bv = b1[col];
#pragma unroll
            for (int mt = 0; mt < 4; mt++) {
#pragma unroll
                for (int r2 = 0; r2 < 4; r2++) {
                    int row = mt * 16 + lg * 4 + r2;
                    float v = fmaxf(acc[mt][nt][r2] + bv, 0.0f);
                    *(u16*)(h1 + row * 512 + ((col * 2) ^ ((row & 7) << 4))) = f2bf(v);
                }
            }
        }
    }
    __syncthreads();

    // ---- GEMM2: h2 = relu(h1 @ W2^T + b2), K=256 ----
    {
        f32x4 acc[4][4] = {};
#pragma unroll
        for (int ks = 0; ks < 8; ks++) {
            bfx8 b[4];
#pragma unroll
            for (int nt = 0; nt < 4; nt++)
                b[nt] = *reinterpret_cast<const bfx8*>(W2 + (size_t)(n0 + nt * 16 + lr) * 256 + ks * 32 + lg * 8);
#pragma unroll
            for (int mt = 0; mt < 4; mt++) {
                bfx8 a = *reinterpret_cast<const bfx8*>(h1 + (mt * 16 + lr) * 512 + ((ks * 64 + lg * 16) ^ key));
#pragma unroll
                for (int nt = 0; nt < 4; nt++)
                    acc[mt][nt] = MFMA16(a, b[nt], acc[mt][nt]);
            }
        }
#pragma unroll
        for (int nt = 0; nt < 4; nt++) {
            int col = n0 + nt * 16 + lr;
            float bv = b2[col];
#pragma unroll
            for (int mt = 0; mt < 4; mt++) {
#pragma unroll
                for (int r2 = 0; r2 < 4; r2++) {
                    int row = mt * 16 + lg * 4 + r2;
                    float v = fmaxf(acc[mt][nt][r2] + bv, 0.0f);
                    *(u16*)(h2 + row * 512 + ((col * 2) ^ ((row & 7) << 4))) = f2bf(v);
                }
            }
        }
    }
    __syncthreads();

    // ---- GEMM3: out = h2 @ W3^T + b3, K=256; epilogue via LDS (h1 dead) ----
    {
        f32x4 acc[4][4] = {};
#pragma unroll
        for (int ks = 0; ks < 8; ks++) {
            bfx8 b[4];
#pragma unroll
            for (int nt = 0; nt < 4; nt++)
                b[nt] = *reinterpret_cast<const bfx8*>(W3 + (size_t)(n0 + nt * 16 + lr) * 256 + ks * 32 + lg * 8);
#pragma unroll
            for (int mt = 0; mt < 4; mt++) {
                bfx8 a = *reinterpret_cast<const bfx8*>(h2 + (mt * 16 + lr) * 512 + ((ks * 64 + lg * 16) ^ key));
#pragma unroll
                for (int nt = 0; nt < 4; nt++)
                    acc[mt][nt] = MFMA16(a, b[nt], acc[mt][nt]);
            }
        }
        u16* ot = (u16*)h1;   // [64][256] staging for coalesced store
#pragma unroll
        for (int nt = 0; nt < 4; nt++) {
            int col = n0 + nt * 16 + lr;
            float bv = b3[col];
#pragma unroll
            for (int mt = 0; mt < 4; mt++) {
#pragma unroll
                for (int r2 = 0; r2 < 4; r2++) {
                    int row = mt * 16 + lg * 4 + r2;
                    ot[row * 256 + col] = f2bf(acc[mt][nt][r2] + bv);
                }
            }
        }
        __syncthreads();
#pragma unroll
        for (int p = 0; p < 8; p++) {
            int idx = p * 256 + tid;           // 2048 chunks of 16 B
            int row = idx >> 5, ck = idx & 31;
            *reinterpret_cast<uint4*>(C + (size_t)row * 256 + ck * 8) =
                *reinterpret_cast<const uint4*>(ot + row * 256 + ck * 8);
        }
    }
}

// ---------------- combined: stats (blocks 0-511) || cvt_rt (blocks 512-2559) ----------
// R14-proven arrangement: long-running stats blocks dispatch first (full residency),
// short rt streamers backfill as they retire. Bodies verbatim.

__global__ __launch_bounds__(256) void stats_rt_kernel(const u16* __restrict__ q,
                                                       const u16* __restrict__ k,
                                                       float2* __restrict__ gso,
                                                       const float* __restrict__ r,
                                                       u16* __restrict__ rt) {
    __shared__ __align__(16) char shmem[64 * 68 * 2];   // 8704 B union

    int tid = threadIdx.x;
    if (blockIdx.x < 512) {
        // ================= stats =================
        int flat = blockIdx.x;
        int sw = (flat & 7) * 64 + (flat >> 3);   // bijective XCD swizzle
        int b = sw >> 5;
        int c0 = (sw & 31) * 64;
        int lane = tid & 63, w = tid >> 6;
        int lr = lane & 15, lg = lane >> 4;
        const u16* qb = q + (size_t)b * NT * DIM;
        const u16* kb = k + (size_t)b * NC * DIM;
        const float A2 = 1.44269504f / 16.0f;

        bfx8 kf[4][8];
#pragma unroll
        for (int j = 0; j < 4; j++)
#pragma unroll
            for (int ks = 0; ks < 8; ks++)
                kf[j][ks] = *reinterpret_cast<const bfx8*>(kb + (size_t)(c0 + j * 16 + lr) * DIM + ks * 32 + lg * 8);

        float m_run[4], l_run[4];
#pragma unroll
        for (int j = 0; j < 4; j++) { m_run[j] = -1e30f; l_run[j] = 0.0f; }

#define LOADQ(dst, ts_) do {                                                        \
    const u16* qrow_ = qb + (size_t)((ts_) * 64 + w * 16 + lr) * DIM;               \
    _Pragma("unroll")                                                               \
    for (int ks_ = 0; ks_ < 8; ks_++)                                               \
        dst[ks_] = *reinterpret_cast<const bfx8*>(qrow_ + ks_ * 32 + lg * 8);       \
} while (0)

#define STEP(aq_) do {                                                              \
    f32x4 sacc[4] = {};                                                             \
    _Pragma("unroll")                                                               \
    for (int ks_ = 0; ks_ < 8; ks_++) {                                             \
        _Pragma("unroll")                                                           \
        for (int j_ = 0; j_ < 4; j_++)                                              \
            sacc[j_] = MFMA16(aq_[ks_], kf[j_][ks_], sacc[j_]);                     \
    }                                                                               \
    _Pragma("unroll")                                                               \
    for (int j_ = 0; j_ < 4; j_++) {                                                \
        f32x4 a_ = sacc[j_];                                                        \
        float mx_ = fmaxf(fmaxf(a_[0], a_[1]), fmaxf(a_[2], a_[3]));                \
        if (mx_ > m_run[j_] + 88.0f) {                                              \
            l_run[j_] *= exp2f((m_run[j_] - mx_) * A2);                             \
            m_run[j_] = mx_;                                                        \
        }                                                                           \
        float t_ = m_run[j_] * A2;                                                  \
        l_run[j_] += exp2f(fmaf(a_[0], A2, -t_)) + exp2f(fmaf(a_[1], A2, -t_))      \
                   + exp2f(fmaf(a_[2], A2, -t_)) + exp2f(fmaf(a_[3], A2, -t_));     \
    }                                                                               \
} while (0)

        bfx8 a0[8], a1[8];
        LOADQ(a0, 0);
        for (int ts = 0; ts < NT / 64; ts += 2) {
            LOADQ(a1, ts + 1);
            STEP(a0);
            if (ts + 2 < NT / 64) LOADQ(a0, ts + 2);
            STEP(a1);
        }
#undef LOADQ
#undef STEP

        // intra-wave combine across the 4 lane-groups, once
#pragma unroll
        for (int j = 0; j < 4; j++) {
            float m = m_run[j], l = l_run[j];
#pragma unroll
            for (int d = 16; d < 64; d <<= 1) {
                float mo = __shfl_xor(m, d);
                float lo = __shfl_xor(l, d);
                float mn = fmaxf(m, mo);
                l = l * exp2f((m - mn) * A2) + lo * exp2f((mo - mn) * A2);
                m = mn;
            }
            m_run[j] = m; l_run[j] = l;
        }

        float* sm = (float*)shmem;        // [4][64]
        float* sl = sm + 256;             // [4][64]
        if (lg == 0) {
#pragma unroll
            for (int j = 0; j < 4; j++) {
                sm[w * 64 + j * 16 + lr] = m_run[j];
                sl[w * 64 + j * 16 + lr] = l_run[j];
            }
        }
        __syncthreads();
        if (tid < 64) {
            float mf = sm[tid];
#pragma unroll
            for (int ww = 1; ww < 4; ww++) mf = fmaxf(mf, sm[ww * 64 + tid]);
            float lf = 0.0f;
#pragma unroll
            for (int ww = 0; ww < 4; ww++) lf += sl[ww * 64 + tid] * exp2f((sm[ww * 64 + tid] - mf) * A2);
            gso[(size_t)b * NC + c0 + tid] = make_float2(mf * A2, 1.0f / lf);
        }
    } else {
        // ================= cvt_rt =================
        int idx = blockIdx.x - 512;
        int b = idx >> 7;
        int d0 = ((idx >> 5) & 3) * 64;
        int c0 = (idx & 31) * 64;
        u16 (*t)[68] = (u16(*)[68])shmem;   // [64][68]
        const float* rb = r + (size_t)b * NC * DIM + d0;
        int cr = tid >> 4, df = (tid & 15) * 4;
#pragma unroll
        for (int p = 0; p < 4; p++) {
            int c = p * 16 + cr;
            float4 v = *reinterpret_cast<const float4*>(rb + (size_t)(c0 + c) * DIM + df);
            t[df + 0][c] = f2bf(v.x);
            t[df + 1][c] = f2bf(v.y);
            t[df + 2][c] = f2bf(v.z);
            t[df + 3][c] = f2bf(v.w);
        }
        __syncthreads();
        u16* rtb = rt + (size_t)b * DIM * NC;
        int dr = tid >> 3, cc = (tid & 7) * 8;
#pragma unroll
        for (int p = 0; p < 2; p++) {
            int d = p * 32 + dr;
            union { u16 u[8]; uint4 v; } pk;
#pragma unroll
            for (int j = 0; j < 8; j++) pk.u[j] = t[d][cc + j];
            *reinterpret_cast<uint4*>(rtb + (size_t)(d0 + d) * NC + c0 + cc) = pk.v;
        }
    }
}

// ---------------- pass 2: R4/R9-proven pipelined attention (127 us, FROZEN) ----------

__global__ __launch_bounds__(256, 2) void attn_kernel(const u16* __restrict__ q,
                                                      const u16* __restrict__ k,
                                                      const u16* __restrict__ rt,
                                                      const float2* __restrict__ gsg_,
                                                      float* __restrict__ out) {
    int flat = blockIdx.x;
    int sw = (flat & 7) * 64 + (flat >> 3);   // each XCD -> 2 batches (k+rt fit L2)
    int b = sw >> 5;
    int t0 = (sw & 31) * 64;
    int tid = threadIdx.x, lane = tid & 63, w = tid >> 6;
    int lr = lane & 15, lg = lane >> 4;
    const u16* qb = q + (size_t)b * NT * DIM;
    const u16* kb = k + (size_t)b * NC * DIM;
    const u16* rtb = rt + (size_t)b * DIM * NC;

    __shared__ float2 gs[NC];                       // 16 KB
    __shared__ __align__(16) u16 kt[2][32 * 256];   // 2 x 16 KB, swizzled K tiles
    __shared__ u16 pl[64][36];                      // P tile, 72B rows

    {
        const float2* gsg = gsg_ + (size_t)b * NC;
        for (int i = tid; i < NC; i += 256) gs[i] = gsg[i];
    }
    __syncthreads();

#define STAGE(nb, cc) do {                                                          \
    const u16* ksrc_ = kb + (size_t)(cc) * DIM;                                     \
    _Pragma("unroll")                                                               \
    for (int i_ = 0; i_ < 4; i_++) {                                                \
        int off_ = ((w * 4 + i_) << 10) + (lane << 4);                              \
        int row_ = off_ >> 9;                                                       \
        int ss_  = ((off_ >> 4) & 31) ^ (row_ & 7);                                 \
        const u16* g_ = ksrc_ + row_ * DIM + ss_ * 8;                               \
        __builtin_amdgcn_global_load_lds(                                           \
            (const __attribute__((address_space(1))) void*)g_,                      \
            (__attribute__((address_space(3))) void*)(&kt[nb][(w * 4 + i_) << 9]),  \
            16, 0, 0);                                                              \
    }                                                                               \
} while (0)

    // prologue: stage tile 0, prefetch rb for tile 0, hoist q
    STAGE(0, 0);
    __builtin_amdgcn_sched_barrier(0);
    bfx8 rb_c[4], rb_n[4];
#pragma unroll
    for (int nt = 0; nt < 4; nt++)
        rb_c[nt] = *reinterpret_cast<const bfx8*>(rtb + (size_t)(w * 64 + nt * 16 + lr) * NC + lg * 8);
    bfx8 aq[8];
#pragma unroll
    for (int ks = 0; ks < 8; ks++)
        aq[ks] = *reinterpret_cast<const bfx8*>(qb + (size_t)(t0 + w * 16 + lr) * DIM + ks * 32 + lg * 8);
    __builtin_amdgcn_sched_barrier(0);
    asm volatile("s_waitcnt vmcnt(12)");   // drain 4 stage issues (12 newer: 4 rb + 8 aq)
    __builtin_amdgcn_s_barrier();
    __builtin_amdgcn_sched_barrier(0);

    const float A = 1.44269504f / 16.0f;   // log2e * (1/sqrt(256))
    const int key = lr & 7;
    f32x4 acc[4][4] = {};
    int cur = 0;

    for (int c0 = 0; c0 < NC; c0 += 32) {
        const bool last = (c0 + 32 >= NC);
        if (!last) STAGE(cur ^ 1, c0 + 32);
        __builtin_amdgcn_sched_barrier(0);
        if (!last) {
#pragma unroll
            for (int nt = 0; nt < 4; nt++)
                rb_n[nt] = *reinterpret_cast<const bfx8*>(rtb + (size_t)(w * 64 + nt * 16 + lr) * NC + (c0 + 32) + lg * 8);
        }

        // S phase: read swizzled kt[cur], 16 MFMAs
        f32x4 s[2] = {};
        {
            const char* kc = (const char*)&kt[cur][0];
#pragma unroll
            for (int ks = 0; ks < 8; ks++) {
                int slot = (ks << 2) | lg;
                bfx8 k0 = *reinterpret_cast<const bfx8*>(kc + (lr << 9) + (((slot ^ key)) << 4));
                bfx8 k1 = *reinterpret_cast<const bfx8*>(kc + ((16 + lr) << 9) + (((slot ^ key)) << 4));
                s[0] = MFMA16(aq[ks], k0, s[0]);
                s[1] = MFMA16(aq[ks], k1, s[1]);
            }
        }
        // P = exp2(S*A - m') * invl -> LDS
#pragma unroll
        for (int j = 0; j < 2; j++) {
            float2 g = gs[c0 + j * 16 + lr];
#pragma unroll
            for (int r = 0; r < 4; r++) {
                float p = exp2f(fmaf(s[j][r], A, -g.x)) * g.y;
                __bf16 h = (__bf16)p;
                pl[w * 16 + lg * 4 + r][j * 16 + lr] = *(u16*)&h;
            }
        }
        __builtin_amdgcn_sched_barrier(0);
        asm volatile("s_waitcnt lgkmcnt(0)");
        __builtin_amdgcn_s_barrier();
        __builtin_amdgcn_sched_barrier(0);

        // PV phase
#pragma unroll
        for (int mt = 0; mt < 4; mt++) {
            bfx8a pa = *reinterpret_cast<const bfx8a*>((const char*)pl + (mt * 16 + lr) * 72 + lg * 16);
#pragma unroll
            for (int nt = 0; nt < 4; nt++)
                acc[mt][nt] = MFMA16((bfx8)pa, rb_c[nt], acc[mt][nt]);
        }

        __builtin_amdgcn_sched_barrier(0);
        asm volatile("s_waitcnt vmcnt(4) lgkmcnt(0)");
        __builtin_amdgcn_s_barrier();
        __builtin_amdgcn_sched_barrier(0);

#pragma unroll
        for (int nt = 0; nt < 4; nt++) rb_c[nt] = rb_n[nt];
        cur ^= 1;
    }
#undef STAGE

    float* ob = out + (size_t)b * NT * DIM;
#pragma unroll
    for (int nt = 0; nt < 4; nt++) {
        int col = w * 64 + nt * 16 + lr;
#pragma unroll
        for (int mt = 0; mt < 4; mt++) {
            int rowb = t0 + mt * 16 + lg * 4;
#pragma unroll
            for (int r = 0; r < 4; r++)
                ob[(size_t)(rowb + r) * DIM + col] = acc[mt][nt][r];
        }
    }
}

// ---------------- launch ----------------

extern "C" void kernel_launch(void* const* d_in, const int* in_sizes, int n_in,
                              void* d_out, int out_size, void* d_ws, size_t ws_size,
                              hipStream_t stream) {
    const float* xc  = (const float*)d_in[0];
    const float* xt  = (const float*)d_in[1];
    const float* ri  = (const float*)d_in[2];
    const float* qw1 = (const float*)d_in[3];  const float* qb1 = (const float*)d_in[4];
    const float* qw2 = (const float*)d_in[5];  const float* qb2 = (const float*)d_in[6];
    const float* qw3 = (const float*)d_in[7];  const float* qb3 = (const float*)d_in[8];
    const float* kw1 = (const float*)d_in[9];  const float* kb1 = (const float*)d_in[10];
    const float* kw2 = (const float*)d_in[11]; const float* kb2 = (const float*)d_in[12];
    const float* kw3 = (const float*)d_in[13]; const float* kb3 = (const float*)d_in[14];

    if (ws_size < ((size_t)66 << 20)) return;  // need ~50 MB

    char* ws = (char*)d_ws;
    u16* q   = (u16*)(ws);                        // 16 MB q bf16
    u16* kk  = (u16*)(ws + ((size_t)16 << 20));   // 16 MB k bf16
    u16* rt  = (u16*)(ws + ((size_t)32 << 20));   // 16 MB rt bf16
    float2* gsb = (float2*)(ws + ((size_t)48 << 20));          // 256 KB col stats
    u16* wbuf = (u16*)(ws + ((size_t)48 << 20) + (512 << 10)); // 640 KB weights
    u16* qw1t = wbuf;
    u16* qw2t = qw1t + 32768;
    u16* qw3t = qw2t + 65536;
    u16* kw1t = qw3t + 65536;
    u16* kw2t = kw1t + 32768;
    u16* kw3t = kw2t + 65536;

    // weights -> transposed bf16 (one launch)
    cvt_w_all<<<dim3(1280), 256, 0, stream>>>(qw1, qw2, qw3, kw1, kw2, kw3,
                                              qw1t, qw2t, qw3t, kw1t, kw2t, kw3t);

    // fused 3-layer MLP, both paths, 64-row tiles (standalone, R14-proven)
    mlp_fused<<<dim3(512, 2), 256, 0, stream>>>(xt, xc,
                                                qw1t, kw1t, qb1, kb1,
                                                qw2t, kw2t, qb2, kb2,
                                                qw3t, kw3t, qb3, kb3,
                                                q, kk);

    // stats (512, dispatched first at full residency) || cvt_rt (2048, backfill)
    stats_rt_kernel<<<dim3(2560), 256, 0, stream>>>(q, kk, gsb, ri, rt);

    // pass 2: attention output
    attn_kernel<<<dim3(512), 256, 0, stream>>>(q, kk, rt, gsb, (float*)d_out);
}